// Round 2
// baseline (374.647 us; speedup 1.0000x reference)
//
#include <hip/hip_runtime.h>

// FastfoodProjection: out = (1/8192) * H * diag(G) * P * H * diag(B) * pad(x)
// per row; H = Hadamard_8192, x rows of 4096 padded to 8192, out rows 8192.
//
// v3 key algebra: H_8192 * [u; 0] = [H_4096*u; H_4096*u]  (unnormalized).
// So FWHT #1 is a 4096-point transform (12 stages, half the data), its output
// implicitly duplicated, and the permutation gather reads lds[perm[j] & 4095].
// All 1/sqrt(N) normalization folds into one final 1/8192 scale (unchanged).
//
// 256 threads/block. Stage 1: 16 regs/thread over 4096 (r = 2m+e, bit 0 of
// logical index j always in e => every LDS exchange is float2/b64):
//   A1: j = m*512 + 2t + e              bits {0, 9..11}   (global load layout)
//   B1: j = t*16  + 2m + e              bits {1..3}
//   C1: j = (t>>3)*128 + m*16 + (t&7)*2 + e   bits {4..6}
//   D1: j = (t>>5)*512 + m*64 + (t&31)*2 + e  bits {7..8}  (final for gather)
// Gather (+G multiply) lands directly in stage-2's first layout. Stage 2:
// 32 regs/thread over 8192, 3 phases (v1's proven structure):
//   C2: j = (t>>4)*512 + m*32 + (t&15)*2 + e  bits {0, 5..8}
//   B2: j = t*32  + 2m + e              bits {1..4}
//   A2: j = m*512 + 2t + e              bits {9..12}  (global store layout)
// Layouts partition j by thread, so read-X -> write-X needs NO barrier:
// 7 __syncthreads total. Per row vs v2: ~40% fewer LDS wave-instructions,
// ~27% fewer butterfly ops, no arithmetic on the structurally-zero half.
// LDS pad +2 words per 32 keeps every phase's b64 pattern conflict-free
// (verified per layout: each bank hit exactly 4x per wave access) and
// preserves 8 B alignment. One 8704-word buffer; stage-1 uses the first
// 4352 padded words, stage-2 reuses the whole (barrier-protected).

constexpr int NT = 256;
constexpr int LDS_WORDS = 8192 + 2 * (8192 / 32); // 8704 words = 34 KB

template <int FIRST_MASK, int NREG>
__device__ __forceinline__ void butterfly(float (&v)[NREG]) {
    #pragma unroll
    for (int b = FIRST_MASK; b < NREG; b <<= 1) {
        #pragma unroll
        for (int r = 0; r < NREG; ++r) {
            if ((r & b) == 0) {
                float a = v[r], c = v[r ^ b];
                v[r]     = a + c;
                v[r ^ b] = a - c;
            }
        }
    }
}

// __launch_bounds__(256, 4): 4 waves/SIMD => VGPR cap 128 (peak live state at
// gather is ~80: 32 data + 32 perm-idx + addressing). LDS caps residency at
// 4 blocks/CU (4 x 34 KB = 136 KB <= 160 KB).
__global__ __launch_bounds__(NT, 4) void fastfood_kernel(
    const float* __restrict__ x, const float* __restrict__ Bv,
    const float* __restrict__ Gv, const int* __restrict__ perm,
    float* __restrict__ out)
{
    __shared__ float lds[LDS_WORDS];
    const int t = threadIdx.x;
    const int row = blockIdx.x;
    const float* xrow = x + (size_t)row * 4096;

    // Padded LDS bases; padw(w) = w + 2*(w>>5) folded per layout (all even =>
    // 8 B alignment holds; strides verified against the padding function):
    const int pA1 = 2 * t + 2 * (t >> 4);                        // + 544*m
    const int pB1 = 16 * t + 2 * (t >> 1);                       // + 2*m
    const int pC1 = 136 * (t >> 3) + 2 * (t & 7);                // + 16m + 2*(m>>1)
    const int pD1 = 544 * (t >> 5) + 2 * (t & 31) + 2 * ((t & 31) >> 4); // + 68*m
    const int wC2 = (t >> 4) * 512 + (t & 15) * 2;               // + 32*m  (logical)
    const int pC2 = 544 * (t >> 4) + 2 * (t & 15);               // + 34*m
    const int pB2 = 34 * t;                                      // + 2*m
    const int wA2 = 2 * t;                                       // + 512*m (logical)
    const int pA2 = 2 * t + 2 * (t >> 4);                        // + 544*m

    // ================= Stage 1: 4096-point FWHT of x*B =================
    float u[16];

    // load + B multiply, layout A1 (all 4096 words real data — no zero pad!)
    #pragma unroll
    for (int m = 0; m < 8; ++m) {
        int j = m * 512 + 2 * t;
        float2 xv = *(const float2*)(xrow + j);
        float2 bv = *(const float2*)(Bv + j);
        u[2 * m]     = xv.x * bv.x;
        u[2 * m + 1] = xv.y * bv.y;
    }

    // phase A1 (bits 0, 9..11)
    butterfly<1, 16>(u);
    #pragma unroll
    for (int m = 0; m < 8; ++m)
        *(float2*)&lds[pA1 + 544 * m] = make_float2(u[2 * m], u[2 * m + 1]);
    __syncthreads();

    // phase B1 (bits 1..3)
    #pragma unroll
    for (int m = 0; m < 8; ++m) {
        float2 d = *(const float2*)&lds[pB1 + 2 * m];
        u[2 * m] = d.x; u[2 * m + 1] = d.y;
    }
    butterfly<2, 16>(u);
    #pragma unroll
    for (int m = 0; m < 8; ++m)   // same addresses we read: no barrier needed
        *(float2*)&lds[pB1 + 2 * m] = make_float2(u[2 * m], u[2 * m + 1]);
    __syncthreads();

    // phase C1 (bits 4..6)
    #pragma unroll
    for (int m = 0; m < 8; ++m) {
        float2 d = *(const float2*)&lds[pC1 + 16 * m + 2 * (m >> 1)];
        u[2 * m] = d.x; u[2 * m + 1] = d.y;
    }
    butterfly<2, 16>(u);
    #pragma unroll
    for (int m = 0; m < 8; ++m)   // same addresses we read: no barrier needed
        *(float2*)&lds[pC1 + 16 * m + 2 * (m >> 1)] = make_float2(u[2 * m], u[2 * m + 1]);
    __syncthreads();

    // phase D1 (bits 7..8 only — bits 0..6, 9..11 already done); prefetch perm
    #pragma unroll
    for (int m = 0; m < 8; ++m) {
        float2 d = *(const float2*)&lds[pD1 + 68 * m];
        u[2 * m] = d.x; u[2 * m + 1] = d.y;
    }
    int2 q[16];
    #pragma unroll
    for (int m = 0; m < 16; ++m)
        q[m] = *(const int2*)(perm + wC2 + 32 * m);
    butterfly<4, 16>(u);          // b=4,8 <-> j bits 7,8
    #pragma unroll
    for (int m = 0; m < 8; ++m)   // same addresses we read: no barrier needed
        *(float2*)&lds[pD1 + 68 * m] = make_float2(u[2 * m], u[2 * m + 1]);
    __syncthreads();

    // ====== permutation gather (duplication-aware) + G multiply =========
    // stage-1 LDS holds FWHT_4096 result; value at logical p (p<8192) is the
    // stage-1 word at (p & 4095). Lands directly in layout C2.
    float v[32];
    #pragma unroll
    for (int m = 0; m < 16; ++m) {
        float2 g = *(const float2*)(Gv + wC2 + 32 * m);
        int wx = q[m].x & 4095;
        int wy = q[m].y & 4095;
        v[2 * m]     = lds[wx + 2 * (wx >> 5)] * g.x;
        v[2 * m + 1] = lds[wy + 2 * (wy >> 5)] * g.y;
    }

    // ================= Stage 2: 8192-point FWHT =========================
    // phase C2 (bits 0, 5..8) — butterfly before the barrier
    butterfly<1, 32>(v);
    __syncthreads();              // all random gathers done before overwrite
    #pragma unroll
    for (int m = 0; m < 16; ++m)
        *(float2*)&lds[pC2 + 34 * m] = make_float2(v[2 * m], v[2 * m + 1]);
    __syncthreads();

    // phase B2 (bits 1..4)
    #pragma unroll
    for (int m = 0; m < 16; ++m) {
        float2 d = *(const float2*)&lds[pB2 + 2 * m];
        v[2 * m] = d.x; v[2 * m + 1] = d.y;
    }
    butterfly<2, 32>(v);
    #pragma unroll
    for (int m = 0; m < 16; ++m)  // same addresses we read: no barrier needed
        *(float2*)&lds[pB2 + 2 * m] = make_float2(v[2 * m], v[2 * m + 1]);
    __syncthreads();

    // phase A2 (bits 9..12)
    #pragma unroll
    for (int m = 0; m < 16; ++m) {
        float2 d = *(const float2*)&lds[pA2 + 544 * m];
        v[2 * m] = d.x; v[2 * m + 1] = d.y;
    }
    butterfly<2, 32>(v);

    // store, fully coalesced (512 B per wave instruction), scale folded
    const float scale = 1.0f / 8192.0f;
    float* orow = out + (size_t)row * 8192;
    #pragma unroll
    for (int m = 0; m < 16; ++m) {
        int j = m * 512 + wA2;
        *(float2*)(orow + j) = make_float2(v[2 * m] * scale, v[2 * m + 1] * scale);
    }
}

extern "C" void kernel_launch(void* const* d_in, const int* in_sizes, int n_in,
                              void* d_out, int out_size, void* d_ws, size_t ws_size,
                              hipStream_t stream) {
    const float* x    = (const float*)d_in[0];
    const float* Bv   = (const float*)d_in[1];
    const float* Gv   = (const float*)d_in[2];
    const int*   perm = (const int*)d_in[3];
    float* out = (float*)d_out;
    fastfood_kernel<<<dim3(8192), dim3(NT), 0, stream>>>(x, Bv, Gv, perm, out);
}